// Round 2
// baseline (135.707 us; speedup 1.0000x reference)
//
#include <hip/hip_runtime.h>
#include <hip/hip_bf16.h>

// CoarsenLattice forward: out[Nc,128] = gather(fine, nbr)[Nc, 9*64] @ W[576,128]
// Strategy: bf16 MFMA GEMM, A gathered per K-tile (one neighbor = 64 cols),
// W pre-transposed to bf16 [128][576] in workspace.

#define N_FINE   1048576
#define N_COARSE 262144
#define VAL_DIM  64
#define FE       9
#define NF       128          // nr_filters
#define KTOT     (FE * VAL_DIM)  // 576

#define BM 128                // coarse rows per block
#define KT 64                 // K tile = one neighbor row
#define THREADS 512           // 8 waves

typedef __attribute__((ext_vector_type(8))) short bf16x8;
typedef __attribute__((ext_vector_type(4))) float f32x4;

__device__ __forceinline__ unsigned short f2bf(float f) {
    unsigned u = __float_as_uint(f);
    unsigned r = (u + 0x7FFFu + ((u >> 16) & 1u)) >> 16;
    return (unsigned short)r;
}

// swizzle byte offset within a 128B row: XOR bits 4-6 with row bits 0-2
#define SWZ(byte, r) ((byte) ^ (((r) & 7) << 4))

__global__ void prep_wt_kernel(const float* __restrict__ w,
                               unsigned short* __restrict__ wT) {
    int i = blockIdx.x * 256 + threadIdx.x;     // over 128*576
    if (i >= NF * KTOT) return;
    int col = i / KTOT;
    int k   = i - col * KTOT;
    wT[i] = f2bf(w[(size_t)k * NF + col]);      // wT[col][k] = w[k][col]
}

__launch_bounds__(THREADS, 2)
__global__ void coarsen_kernel(const float* __restrict__ fine,
                               const int* __restrict__ nbr,
                               const unsigned short* __restrict__ wT,
                               float* __restrict__ out) {
    __shared__ __align__(16) unsigned short sA[BM * KT];   // 16 KB, swizzled
    __shared__ __align__(16) unsigned short sW[NF * KT];   // 16 KB, swizzled
    __shared__ int sIdx[BM * FE];                          // 4.5 KB

    const int t = threadIdx.x;
    const int bRow = blockIdx.x * BM;

    // preload this block's neighbor indices (contiguous, coalesced)
    for (int i = t; i < BM * FE; i += THREADS)
        sIdx[i] = nbr[(size_t)bRow * FE + i];

    const int lane   = t & 63;
    const int wave   = t >> 6;          // 0..7
    const int wm     = wave >> 1;       // 0..3 -> M offset wm*32
    const int wn     = wave & 1;        // 0..1 -> N offset wn*64
    const int l15    = lane & 15;
    const int lhi    = lane >> 4;       // 0..3

    // staging decomposition for A: 16 lanes per fine row (float4 each)
    const int lane16 = t & 15;          // k-chunk within row
    const int rgrp   = t >> 4;          // 0..31

    f32x4 acc[2][4];
#pragma unroll
    for (int i = 0; i < 2; ++i)
#pragma unroll
        for (int j = 0; j < 4; ++j)
            acc[i][j] = (f32x4)0.0f;

    char* const baseA = (char*)sA;
    char* const baseW = (char*)sW;

    __syncthreads();   // sIdx ready

    for (int fe = 0; fe < FE; ++fe) {
        if (fe) __syncthreads();   // previous compute done before overwrite

        // ---- stage A tile: BM rows x 64 bf16 (gather + convert) ----
#pragma unroll
        for (int p = 0; p < 4; ++p) {
            int row = rgrp + p * 32;
            int idx = sIdx[row * FE + fe];
            const float4 v = *(const float4*)(fine + (size_t)idx * VAL_DIM + lane16 * 4);
            ushort4 h;
            h.x = f2bf(v.x); h.y = f2bf(v.y); h.z = f2bf(v.z); h.w = f2bf(v.w);
            int off = row * 128 + lane16 * 8;
            *(ushort4*)(baseA + SWZ(off, row)) = h;
        }

        // ---- stage W tile: 128 cols x 64 bf16 from wT[col][fe*64 + k] ----
#pragma unroll
        for (int c = t; c < 1024; c += THREADS) {   // 1024 chunks of 16B
            int col = c >> 3;
            int kc  = c & 7;
            const int4 v = *(const int4*)(wT + (size_t)col * KTOT + fe * KT + kc * 8);
            int off = col * 128 + kc * 16;
            *(int4*)(baseW + SWZ(off, col)) = v;
        }

        __syncthreads();

        // ---- compute: 2 k-steps of K=32 ----
#pragma unroll
        for (int ks = 0; ks < 2; ++ks) {
            const int kbyte = ks * 64 + lhi * 16;
            bf16x8 a[2], b[4];
#pragma unroll
            for (int fm = 0; fm < 2; ++fm) {
                int row = wm * 32 + fm * 16 + l15;
                a[fm] = *(const bf16x8*)(baseA + SWZ(row * 128 + kbyte, row));
            }
#pragma unroll
            for (int fn = 0; fn < 4; ++fn) {
                int col = wn * 64 + fn * 16 + l15;
                b[fn] = *(const bf16x8*)(baseW + SWZ(col * 128 + kbyte, col));
            }
#pragma unroll
            for (int fm = 0; fm < 2; ++fm)
#pragma unroll
                for (int fn = 0; fn < 4; ++fn)
                    acc[fm][fn] = __builtin_amdgcn_mfma_f32_16x16x32_bf16(
                        a[fm], b[fn], acc[fm][fn], 0, 0, 0);
        }
    }

    // ---- epilogue: C[row=(lhi*4+j)][col=l15] per 16x16 frag ----
#pragma unroll
    for (int fm = 0; fm < 2; ++fm)
#pragma unroll
        for (int fn = 0; fn < 4; ++fn)
#pragma unroll
            for (int j = 0; j < 4; ++j) {
                int row = bRow + wm * 32 + fm * 16 + lhi * 4 + j;
                int col = wn * 64 + fn * 16 + l15;
                out[(size_t)row * NF + col] = acc[fm][fn][j];
            }
}

extern "C" void kernel_launch(void* const* d_in, const int* in_sizes, int n_in,
                              void* d_out, int out_size, void* d_ws, size_t ws_size,
                              hipStream_t stream) {
    const float* fine = (const float*)d_in[0];
    const int*   nbr  = (const int*)d_in[1];
    const float* w    = (const float*)d_in[2];
    float* out = (float*)d_out;

    unsigned short* wT = (unsigned short*)d_ws;   // 128*576 bf16 = 144 KB

    prep_wt_kernel<<<(NF * KTOT + 255) / 256, 256, 0, stream>>>(w, wT);
    coarsen_kernel<<<N_COARSE / BM, THREADS, 0, stream>>>(fine, nbr, wT, out);
}